// Round 3
// baseline (62.174 us; speedup 1.0000x reference)
//
#include <hip/hip_runtime.h>

#define OUT_F 11008
#define IN_F  4096
#define KSTEP 128
#define NSTEP (IN_F / KSTEP)   // 32 steps; per step each lane handles 2 k (float2/int2)

// 4 output rows per wave, full K per wave. Depth-1 software pipeline with
// issue-order == use-order so the in-order vmcnt wait for step t's data never
// drains step t+1's prefetch. zero-point folded: out = s*(dot - zp*rowsum)+bias,
// rowsum computed in-loop. KSTEP=128 keeps both double buffers at half the
// VGPR cost of R1 -> under the 128-reg occupancy cliff (4 waves/SIMD).
__global__ __launch_bounds__(256, 4) void qlinear_kernel(
        const float* __restrict__ in, const int* __restrict__ qw,
        const int* __restrict__ zp, const float* __restrict__ scale,
        const float* __restrict__ bias, float* __restrict__ out) {
    const int lane  = threadIdx.x & 63;
    const int group = blockIdx.x * 4 + (threadIdx.x >> 6);
    const int row0  = group * 4;
    const int l2    = lane * 2;

    float acc[4][8];
    float asum[8];
    #pragma unroll
    for (int r = 0; r < 4; ++r)
        #pragma unroll
        for (int b = 0; b < 8; ++b) acc[r][b] = 0.f;
    #pragma unroll
    for (int b = 0; b < 8; ++b) asum[b] = 0.f;

    float2 x0_[8], x1_[8];   // x step double-buffer (named -> static indexing)
    int2   w0_[4], w1_[4];   // weight step double-buffer

    const size_t wbase = (size_t)row0 * IN_F + l2;

    // clamp instead of branch on the last iterations (redundant reload of the
    // final step; keeps the pipeline branch-free and uniform)
#define LOAD_X(XB, S) do {                                                  \
        const int s_ = ((S) < NSTEP) ? (S) : (NSTEP - 1);                   \
        const int o_ = s_ * KSTEP + l2;                                     \
        _Pragma("unroll")                                                   \
        for (int b = 0; b < 8; ++b)                                         \
            XB[b] = *reinterpret_cast<const float2*>(in + b * IN_F + o_);   \
    } while (0)

#define LOAD_W(WB, S) do {                                                  \
        const int s_ = ((S) < NSTEP) ? (S) : (NSTEP - 1);                   \
        const size_t o_ = wbase + (size_t)(s_ * KSTEP);                     \
        WB[0] = *reinterpret_cast<const int2*>(qw + o_);                    \
        WB[1] = *reinterpret_cast<const int2*>(qw + o_ + IN_F);             \
        WB[2] = *reinterpret_cast<const int2*>(qw + o_ + 2 * IN_F);         \
        WB[3] = *reinterpret_cast<const int2*>(qw + o_ + 3 * IN_F);         \
    } while (0)

#define FMA_STEP(XB, WB) do {                                               \
        const float g0x = (float)WB[0].x, g0y = (float)WB[0].y;             \
        const float g1x = (float)WB[1].x, g1y = (float)WB[1].y;             \
        const float g2x = (float)WB[2].x, g2y = (float)WB[2].y;             \
        const float g3x = (float)WB[3].x, g3y = (float)WB[3].y;             \
        _Pragma("unroll")                                                   \
        for (int b = 0; b < 8; ++b) {                                       \
            const float2 xv = XB[b];                                        \
            asum[b]   += xv.x + xv.y;                                       \
            acc[0][b] += g0x * xv.x + g0y * xv.y;                           \
            acc[1][b] += g1x * xv.x + g1y * xv.y;                           \
            acc[2][b] += g2x * xv.x + g2y * xv.y;                           \
            acc[3][b] += g3x * xv.x + g3y * xv.y;                           \
        }                                                                   \
    } while (0)

    // prologue: step 0 into buffer 0
    LOAD_X(x0_, 0);
    LOAD_W(w0_, 0);

    #pragma unroll 1
    for (int j = 0; j < NSTEP / 2; ++j) {
        const int s = 2 * j;
        LOAD_X(x1_, s + 1); LOAD_W(w1_, s + 1); FMA_STEP(x0_, w0_);
        LOAD_X(x0_, s + 2); LOAD_W(w0_, s + 2); FMA_STEP(x1_, w1_);
    }

#undef LOAD_X
#undef LOAD_W
#undef FMA_STEP

    // --- cross-lane reduce of 32 dot-accumulators (register-halving tree) ---
    float v[32];
    #pragma unroll
    for (int r = 0; r < 4; ++r)
        #pragma unroll
        for (int b = 0; b < 8; ++b) v[r * 8 + b] = acc[r][b];

    #pragma unroll
    for (int k = 0; k < 5; ++k) {
        const bool hi = (lane >> k) & 1;
        const int  n  = 32 >> k;
        #pragma unroll
        for (int i = 0; i < 32; ++i) {
            if (i < n / 2) {
                float keep = hi ? v[2 * i + 1] : v[2 * i];
                float send = hi ? v[2 * i]     : v[2 * i + 1];
                v[i] = keep + __shfl_xor(send, 1 << k);
            }
        }
    }
    const float total = v[0] + __shfl_xor(v[0], 32);

    // --- reduce the 8 input row-sums ---
    float s8[8];
    #pragma unroll
    for (int b = 0; b < 8; ++b) s8[b] = asum[b];
    #pragma unroll
    for (int k = 0; k < 3; ++k) {
        const bool hi = (lane >> k) & 1;
        const int  n  = 8 >> k;
        #pragma unroll
        for (int i = 0; i < 8; ++i) {
            if (i < n / 2) {
                float keep = hi ? s8[2 * i + 1] : s8[2 * i];
                float send = hi ? s8[2 * i]     : s8[2 * i + 1];
                s8[i] = keep + __shfl_xor(send, 1 << k);
            }
        }
    }
    float S = s8[0];
    S += __shfl_xor(S, 8);
    S += __shfl_xor(S, 16);
    S += __shfl_xor(S, 32);   // full rowsum of batch (lane&7)

    if (lane < 32) {
        const int r = lane >> 3;
        const int b = lane & 7;
        const int o = row0 + r;
        const float res = scale[o] * (total - (float)zp[o] * S) + bias[o];
        out[(size_t)b * OUT_F + o] = res;
    }
}

extern "C" void kernel_launch(void* const* d_in, const int* in_sizes, int n_in,
                              void* d_out, int out_size, void* d_ws, size_t ws_size,
                              hipStream_t stream) {
    const float* in    = (const float*)d_in[0];
    const int*   qw    = (const int*)  d_in[1];
    const int*   zp    = (const int*)  d_in[2];
    const float* scale = (const float*)d_in[3];
    const float* bias  = (const float*)d_in[4];
    float*       out   = (float*)d_out;

    const int groups = OUT_F / 4;        // 2752
    const int blocks = groups / 4;       // 688 blocks x 4 waves
    qlinear_kernel<<<blocks, 256, 0, stream>>>(in, qw, zp, scale, bias, out);
}